// Round 13
// baseline (211.487 us; speedup 1.0000x reference)
//
#include <hip/hip_runtime.h>
#include <hip/hip_fp16.h>
#include <math.h>

#define HH 4      // heads
#define DD 32     // out dim per head
#define HD 128    // H*D
#define INF 128   // node in_dim
#define EDF 64    // edge feat dim
#define NEG 0.01f
#define NB 256    // scan blocks
#define CHUNK 64  // edges per k_agg chunk
#define GS_AGG   2048
#define GS_NODES 1024
#define GS_TC    1024

// ---- DPP helpers (VALU, no LDS) -----------------------------------------
template <int CTRL>
__device__ __forceinline__ float dpp_add(float v) {
    int t = __builtin_amdgcn_update_dpp(0, __float_as_int(v), CTRL, 0xF, 0xF, true);
    return v + __int_as_float(t);
}
__device__ __forceinline__ float red16(float v) {
    v = dpp_add<0xB1>(v);    // quad_perm(1,0,3,2)
    v = dpp_add<0x4E>(v);    // quad_perm(2,3,0,1)
    v = dpp_add<0x141>(v);   // row_half_mirror
    v = dpp_add<0x140>(v);   // row_mirror
    return v;
}

// ---- precompute collapsed weight matrices (+ zero deg) ------------------
__global__ void k_pre(const float* __restrict__ Wn, const float* __restrict__ We,
                      const float* __restrict__ Wa, const float* __restrict__ Wo,
                      float* __restrict__ WnA, float* __restrict__ WnB,
                      float* __restrict__ WeC, float* __restrict__ WeWo,
                      float* __restrict__ WnWo, int* __restrict__ deg, int N) {
    int b = blockIdx.x, tid = threadIdx.x;   // (25 + ceil(N/512)) blocks x 512
    if (b >= 25) {
        int i = (b - 25) * 512 + tid;
        if (i < N) deg[i] = 0;
        return;
    }
    if (b < 16) {
        int t = b * 512 + tid;               // t = (h*64+k)*32 + o
        int j = t >> 5, o = t & 31;
        int h = j >> 6, k = j & 63;
        float a = 0.f;
        for (int d = 0; d < DD; ++d)
            a += We[k * HD + h * DD + d] * Wo[(h * DD + d) * DD + o];
        WeWo[t] = a;
    } else if (b < 24) {
        int u = (b - 16) * 512 + tid;        // u = k*32 + o
        int k = u >> 5, o = u & 31;
        float a = 0.f;
        for (int d = 0; d < HD; ++d)
            a += Wn[k * HD + d] * Wo[d * DD + o];
        WnWo[u] = a;
    } else {
        int k = tid >> 2, h = tid & 3;
        float a = 0.f, bb = 0.f;
        for (int d = 0; d < DD; ++d) {
            float w = Wn[k * HD + h * DD + d];
            a += w * Wa[d];
            bb += w * Wa[DD + d];
        }
        WnA[k * HH + h] = a;
        WnB[k * HH + h] = bb;
        if (k < EDF) {
            float c = 0.f;
            for (int d = 0; d < DD; ++d)
                c += We[k * HD + h * DD + d] * (Wa[d] + Wa[DD + d]);
            WeC[k * HH + h] = c;
        }
    }
}

// ---- per-node attention scalars an,bn (wave per node, grid-stride) ------
__global__ void k_nodes(const float* __restrict__ X, const float* __restrict__ WnA,
                        const float* __restrict__ WnB, float* __restrict__ an,
                        float* __restrict__ bn, int N) {
    int wave = threadIdx.x >> 6, lane = threadIdx.x & 63;
    float4 wa0 = *(const float4*)(WnA + lane * 8);
    float4 wa1 = *(const float4*)(WnA + lane * 8 + 4);
    float4 wb0 = *(const float4*)(WnB + lane * 8);
    float4 wb1 = *(const float4*)(WnB + lane * 8 + 4);
    int stride = gridDim.x * 4;
    for (int n = blockIdx.x * 4 + wave; n < N; n += stride) {
        float2 x2 = *(const float2*)(X + (size_t)n * INF + lane * 2);
        float pa[HH], pb[HH];
        pa[0] = x2.x * wa0.x + x2.y * wa1.x;
        pa[1] = x2.x * wa0.y + x2.y * wa1.y;
        pa[2] = x2.x * wa0.z + x2.y * wa1.z;
        pa[3] = x2.x * wa0.w + x2.y * wa1.w;
        pb[0] = x2.x * wb0.x + x2.y * wb1.x;
        pb[1] = x2.x * wb0.y + x2.y * wb1.y;
        pb[2] = x2.x * wb0.z + x2.y * wb1.z;
        pb[3] = x2.x * wb0.w + x2.y * wb1.w;
#pragma unroll
        for (int off = 32; off; off >>= 1)
#pragma unroll
            for (int h = 0; h < HH; ++h) {
                pa[h] += __shfl_xor(pa[h], off);
                pb[h] += __shfl_xor(pb[h], off);
            }
        if (lane == 0)
#pragma unroll
            for (int h = 0; h < HH; ++h) {
                an[(size_t)n * HH + h] = pa[h];
                bn[(size_t)n * HH + h] = pb[h];
            }
    }
}

// ---- CSR build ----------------------------------------------------------
__global__ void k_hist(const int* __restrict__ dst, int* __restrict__ deg,
                       int* __restrict__ rank, int E) {
    int e = blockIdx.x * blockDim.x + threadIdx.x;
    if (e < E) rank[e] = atomicAdd(&deg[dst[e]], 1);
}
__global__ void k_scan1(const int* __restrict__ deg, int* __restrict__ partial,
                        int N, int chunk) {
    __shared__ int s[256];
    int tid = threadIdx.x;
    int i = blockIdx.x * chunk + tid;
    int v = (tid < chunk && i < N) ? deg[i] : 0;
    s[tid] = v; __syncthreads();
    for (int off = 128; off; off >>= 1) {
        if (tid < off) s[tid] += s[tid + off];
        __syncthreads();
    }
    if (tid == 0) partial[blockIdx.x] = s[0];
}
__global__ void k_scan2(const int* __restrict__ partial, int* __restrict__ pscan) {
    __shared__ int s[NB];
    int tid = threadIdx.x;
    int v = partial[tid];
    s[tid] = v; __syncthreads();
    for (int off = 1; off < NB; off <<= 1) {
        int t = (tid >= off) ? s[tid - off] : 0;
        __syncthreads();
        s[tid] += t;
        __syncthreads();
    }
    pscan[tid] = s[tid] - v;   // exclusive
}
// packs nd[i] = {offs, deg}
__global__ void k_scan3(const int* __restrict__ deg, const int* __restrict__ pscan,
                        int* __restrict__ offs, int2* __restrict__ nd,
                        int N, int chunk) {
    __shared__ int s[256];
    int tid = threadIdx.x;
    int i = blockIdx.x * chunk + tid;
    int v = (tid < chunk && i < N) ? deg[i] : 0;
    s[tid] = v; __syncthreads();
    for (int off = 1; off < 256; off <<= 1) {
        int t = (tid >= off) ? s[tid - off] : 0;
        __syncthreads();
        s[tid] += t;
        __syncthreads();
    }
    if (tid < chunk && i < N) {
        int o = pscan[blockIdx.x] + s[tid] - v;   // exclusive
        offs[i] = o;
        nd[i] = make_int2(o, v);
    }
}
// permutation + an-prescatter: eids[p]=e, anp[p]=an[src[e]]
__global__ void k_perm(const int* __restrict__ src, const int* __restrict__ dst,
                       const int* __restrict__ offs, const int* __restrict__ rank,
                       const float* __restrict__ an, int* __restrict__ eids,
                       float4* __restrict__ anp, int E) {
    int e = blockIdx.x * blockDim.x + threadIdx.x;
    if (e < E) {
        int p = offs[dst[e]] + rank[e];
        eids[p] = e;
        anp[p] = *(const float4*)(an + (size_t)src[e] * HH);
    }
}

// ---- pure streaming transcode: EF fp32 -> EF16 fp16, storage order ------
// Coalesced read (256B/row) + coalesced write (128B/row). No indices, no
// scatter. Halves the bytes k_agg must randomly gather (the ~1.5TB/s term).
__global__ void k_tc16(const float* __restrict__ EF, __half* __restrict__ EF16,
                       long long total4) {   // total float4 count = E*16
    long long i = (long long)blockIdx.x * blockDim.x + threadIdx.x;
    long long stride = (long long)gridDim.x * blockDim.x;
    for (; i < total4; i += stride) {
        float4 x4 = ((const float4*)EF)[i];
        __half2 h01 = __floats2half2_rn(x4.x, x4.y);
        __half2 h23 = __floats2half2_rn(x4.z, x4.w);
        uint2 u = make_uint2(*(unsigned*)&h01, *(unsigned*)&h23);
        ((uint2*)EF16)[i] = u;
    }
}

// ---- single-pass: logits + softmax + aggregate + epilogue GEMM ----------
// v13 = R9's fused structure verbatim, except the EF row gather is fp16
// (8B/lane uint2 instead of 16B float4): random-gathered bytes halved.
__global__ void k_agg(const __half* __restrict__ EF16, const float4* __restrict__ anp,
                      const float* __restrict__ bn, const float* __restrict__ WeC,
                      const int* __restrict__ eids, const int2* __restrict__ nd,
                      const float* __restrict__ WW, const float* __restrict__ X,
                      const float* __restrict__ WnWo, float* __restrict__ out, int N) {
    __shared__ float ww_s[256 * 32];         // WeWo [j][o], 32KB
    __shared__ float pw[4][256];             // per-wave: anp staging / G
    __shared__ int   ebuf[4][CHUNK];
    for (int i = threadIdx.x; i < 256 * 32; i += 256)
        ww_s[i] = WW[i];
    __syncthreads();                         // once per block

    int wave = threadIdx.x >> 6, lane = threadIdx.x & 63;
    int g = lane >> 4, q = lane & 15;
    int r8 = lane >> 3, c4 = (lane & 7) * 4; // epilogue: row-in-group, col base
    // wc[c][h] = WeC[(q*4+c)*4+h]; 1KB, L1-resident
    float4 c0 = *(const float4*)(WeC + (q * 4 + 0) * 4);
    float4 c1 = *(const float4*)(WeC + (q * 4 + 1) * 4);
    float4 c2w = *(const float4*)(WeC + (q * 4 + 2) * 4);
    float4 c3 = *(const float4*)(WeC + (q * 4 + 3) * 4);
    int stride = gridDim.x * 4;
    for (int n = blockIdx.x * 4 + wave; n < N; n += stride) {
        int2 sd = nd[n];
        int st = sd.x, dn = sd.y;
        if (dn == 0) {                       // rare: out = relu(X @ WnWo)
            if (lane < 32) {
                float a = 0.f;
                for (int k = 0; k < INF; ++k)
                    a += X[(size_t)n * INF + k] * WnWo[k * DD + lane];
                out[(size_t)n * DD + lane] = fmaxf(a, 0.f);
            }
            continue;
        }
        float4 bn4 = *(const float4*)(bn + (size_t)n * HH);
        float4* abuf = (float4*)pw[wave];
        float4 gh0 = make_float4(0.f, 0.f, 0.f, 0.f);   // head h, feats 4q..4q+3
        float4 gh1 = gh0, gh2 = gh0, gh3 = gh0;
        float den0 = 0.f, den1 = 0.f, den2 = 0.f, den3 = 0.f;
        for (int r0 = 0; r0 < dn; r0 += CHUNK) {
            int cnt = dn - r0; if (cnt > CHUNK) cnt = CHUNK;
            {
                int l2 = lane < cnt ? lane : cnt - 1;
                ebuf[wave][lane] = eids[st + r0 + l2];
                abuf[lane] = anp[(size_t)(st + r0 + l2)];
            }
            int nb4 = (cnt + 3) >> 2;
            // 2-deep prefetch of 128B fp16 rows (group g -> edge i*4+g)
            int e = ebuf[wave][g];
            uint2 xAu = *(const uint2*)(EF16 + (size_t)e * EDF + q * 4);
            e = ebuf[wave][(4 + g) & 63];
            uint2 xBu = *(const uint2*)(EF16 + (size_t)e * EDF + q * 4);
            for (int i = 0; i < nb4; ++i) {
                e = ebuf[wave][((i + 2) * 4 + g) & 63];
                uint2 xCu = *(const uint2*)(EF16 + (size_t)e * EDF + q * 4);
                float4 a4 = abuf[i * 4 + g];         // 16-way LDS broadcast
                bool valid = (i * 4 + g) < cnt;
                // dequant fp16 -> fp32
                float2 f01 = __half22float2(*(const __half2*)&xAu.x);
                float2 f23 = __half22float2(*(const __half2*)&xAu.y);
                float xx = f01.x, xy = f01.y, xz = f23.x, xw = f23.y;
                // logits: DPP 16-lane reduce of EF . WeC per head
                float ae0 = red16(xx * c0.x + xy * c1.x + xz * c2w.x + xw * c3.x);
                float ae1 = red16(xx * c0.y + xy * c1.y + xz * c2w.y + xw * c3.y);
                float ae2 = red16(xx * c0.z + xy * c1.z + xz * c2w.z + xw * c3.z);
                float ae3 = red16(xx * c0.w + xy * c1.w + xz * c2w.w + xw * c3.w);
                float l0 = a4.x + bn4.x + ae0;
                float l1 = a4.y + bn4.y + ae1;
                float l2 = a4.z + bn4.z + ae2;
                float l3 = a4.w + bn4.w + ae3;
                float w0 = valid ? __expf(l0 > 0.f ? l0 : NEG * l0) : 0.f;
                float w1 = valid ? __expf(l1 > 0.f ? l1 : NEG * l1) : 0.f;
                float w2 = valid ? __expf(l2 > 0.f ? l2 : NEG * l2) : 0.f;
                float w3 = valid ? __expf(l3 > 0.f ? l3 : NEG * l3) : 0.f;
                gh0.x += w0 * xx; gh0.y += w0 * xy; gh0.z += w0 * xz; gh0.w += w0 * xw;
                gh1.x += w1 * xx; gh1.y += w1 * xy; gh1.z += w1 * xz; gh1.w += w1 * xw;
                gh2.x += w2 * xx; gh2.y += w2 * xy; gh2.z += w2 * xz; gh2.w += w2 * xw;
                gh3.x += w3 * xx; gh3.y += w3 * xy; gh3.z += w3 * xz; gh3.w += w3 * xw;
                den0 += w0; den1 += w1; den2 += w2; den3 += w3;
                xAu = xBu; xBu = xCu;
            }
        }
        // cross-group combine (q preserved under xor 16/32)
#pragma unroll
        for (int off = 16; off < 64; off <<= 1) {
            gh0.x += __shfl_xor(gh0.x, off); gh0.y += __shfl_xor(gh0.y, off);
            gh0.z += __shfl_xor(gh0.z, off); gh0.w += __shfl_xor(gh0.w, off);
            gh1.x += __shfl_xor(gh1.x, off); gh1.y += __shfl_xor(gh1.y, off);
            gh1.z += __shfl_xor(gh1.z, off); gh1.w += __shfl_xor(gh1.w, off);
            gh2.x += __shfl_xor(gh2.x, off); gh2.y += __shfl_xor(gh2.y, off);
            gh2.z += __shfl_xor(gh2.z, off); gh2.w += __shfl_xor(gh2.w, off);
            gh3.x += __shfl_xor(gh3.x, off); gh3.y += __shfl_xor(gh3.y, off);
            gh3.z += __shfl_xor(gh3.z, off); gh3.w += __shfl_xor(gh3.w, off);
            den0 += __shfl_xor(den0, off); den1 += __shfl_xor(den1, off);
            den2 += __shfl_xor(den2, off); den3 += __shfl_xor(den3, off);
        }
        // ---- stage normalized G: lane-linear float4 write (no conflicts) -
        float* G = pw[wave];                 // abuf no longer needed
        float dsel = g == 0 ? den0 : g == 1 ? den1 : g == 2 ? den2 : den3;
        float4 gsel = g == 0 ? gh0 : g == 1 ? gh1 : g == 2 ? gh2 : gh3;
        float inv = 1.f / dsel;
        float4 gn;
        gn.x = gsel.x * inv; gn.y = gsel.y * inv;
        gn.z = gsel.z * inv; gn.w = gsel.w * inv;
        *(float4*)&G[lane * 4] = gn;         // lane*4 == g*64+q*4
        // ---- epilogue GEMM: linear WW reads + broadcast G ---------------
        float4 acc = make_float4(0.f, 0.f, 0.f, 0.f);
#pragma unroll 8
        for (int s = 0; s < 32; ++s) {
            int row = s * 8 + r8;
            float gv = G[row];                              // 8-way multicast
            float4 w4 = *(const float4*)&ww_s[row * 32 + c4]; // linear 1KB/instr
            acc.x += gv * w4.x;
            acc.y += gv * w4.y;
            acc.z += gv * w4.z;
            acc.w += gv * w4.w;
        }
#pragma unroll
        for (int off = 8; off < 64; off <<= 1) {
            acc.x += __shfl_xor(acc.x, off);
            acc.y += __shfl_xor(acc.y, off);
            acc.z += __shfl_xor(acc.z, off);
            acc.w += __shfl_xor(acc.w, off);
        }
        if (lane < 8) {
            float4 o_;
            o_.x = fmaxf(acc.x, 0.f);
            o_.y = fmaxf(acc.y, 0.f);
            o_.z = fmaxf(acc.z, 0.f);
            o_.w = fmaxf(acc.w, 0.f);
            *(float4*)(out + (size_t)n * DD + lane * 4) = o_;
        }
    }
}

extern "C" void kernel_launch(void* const* d_in, const int* in_sizes, int n_in,
                              void* d_out, int out_size, void* d_ws, size_t ws_size,
                              hipStream_t stream) {
    const float* node_feats = (const float*)d_in[0];
    const float* edge_feats = (const float*)d_in[1];
    const int*   src        = (const int*)d_in[2];
    const int*   dst        = (const int*)d_in[3];
    const float* Wn         = (const float*)d_in[4];
    const float* We         = (const float*)d_in[5];
    const float* Wa         = (const float*)d_in[6];
    const float* Wo         = (const float*)d_in[7];
    float* out = (float*)d_out;
    int N = in_sizes[0] / INF;
    int E = in_sizes[2];

    char* p = (char*)d_ws;
    auto alloc = [&](size_t bytes) {
        char* r = p;
        p += (bytes + 255) & ~(size_t)255;
        return r;
    };
    float* WnA    = (float*)alloc((size_t)INF * HH * 4);
    float* WnB    = (float*)alloc((size_t)INF * HH * 4);
    float* WeC    = (float*)alloc((size_t)EDF * HH * 4);
    float* WeWo   = (float*)alloc((size_t)EDF * HH * DD * 4);
    float* WnWo   = (float*)alloc((size_t)INF * DD * 4);
    float* an     = (float*)alloc((size_t)N * HH * 4);
    float* bn     = (float*)alloc((size_t)N * HH * 4);
    float4* anp   = (float4*)alloc((size_t)E * 16);
    __half* EF16  = (__half*)alloc((size_t)E * EDF * 2);
    int* deg      = (int*)alloc((size_t)N * 4);
    int* offs     = (int*)alloc((size_t)N * 4);
    int2* nd      = (int2*)alloc((size_t)N * 8);
    int* rank     = (int*)alloc((size_t)E * 4);
    int* eids     = (int*)alloc((size_t)E * 4);
    int* partial  = (int*)alloc((size_t)NB * 4);
    int* pscan    = (int*)alloc((size_t)NB * 4);

    int chunk = (N + NB - 1) / NB;
    int preblk = 25 + (N + 511) / 512;

    hipLaunchKernelGGL(k_pre, dim3(preblk), dim3(512), 0, stream,
                       Wn, We, Wa, Wo, WnA, WnB, WeC, WeWo, WnWo, deg, N);
    // transcode is CSR-independent: run early, purely streaming
    hipLaunchKernelGGL(k_tc16, dim3(GS_TC), dim3(256), 0, stream,
                       edge_feats, EF16, (long long)E * 16);
    hipLaunchKernelGGL(k_nodes, dim3(GS_NODES), dim3(256), 0, stream,
                       node_feats, WnA, WnB, an, bn, N);
    hipLaunchKernelGGL(k_hist, dim3((E + 255) / 256), dim3(256), 0, stream,
                       dst, deg, rank, E);
    hipLaunchKernelGGL(k_scan1, dim3(NB), dim3(256), 0, stream, deg, partial, N, chunk);
    hipLaunchKernelGGL(k_scan2, dim3(1), dim3(NB), 0, stream, partial, pscan);
    hipLaunchKernelGGL(k_scan3, dim3(NB), dim3(256), 0, stream, deg, pscan, offs, nd, N, chunk);
    hipLaunchKernelGGL(k_perm, dim3((E + 255) / 256), dim3(256), 0, stream,
                       src, dst, offs, rank, an, eids, anp, E);
    hipLaunchKernelGGL(k_agg, dim3(GS_AGG), dim3(256), 0, stream,
                       EF16, anp, bn, WeC, eids, nd, WeWo, node_feats, WnWo, out, N);
}

// Round 15
// 166.098 us; speedup vs baseline: 1.2733x; 1.2733x over previous
//
#include <hip/hip_runtime.h>
#include <math.h>

#define HH 4      // heads
#define DD 32     // out dim per head
#define HD 128    // H*D
#define INF 128   // node in_dim
#define EDF 64    // edge feat dim
#define NEG 0.01f
#define NB 256    // scan blocks
#define CHUNK 64  // edges per k_agg chunk
#define GS_AGG   2048
#define GS_NODES 1024

// ---- DPP helpers (VALU, no LDS) -----------------------------------------
template <int CTRL>
__device__ __forceinline__ float dpp_add(float v) {
    int t = __builtin_amdgcn_update_dpp(0, __float_as_int(v), CTRL, 0xF, 0xF, true);
    return v + __int_as_float(t);
}
__device__ __forceinline__ float red16(float v) {
    v = dpp_add<0xB1>(v);    // quad_perm(1,0,3,2)
    v = dpp_add<0x4E>(v);    // quad_perm(2,3,0,1)
    v = dpp_add<0x141>(v);   // row_half_mirror
    v = dpp_add<0x140>(v);   // row_mirror
    return v;
}

// ---- precompute collapsed weight matrices (+ zero deg) ------------------
__global__ void k_pre(const float* __restrict__ Wn, const float* __restrict__ We,
                      const float* __restrict__ Wa, const float* __restrict__ Wo,
                      float* __restrict__ WnA, float* __restrict__ WnB,
                      float* __restrict__ WeC, float* __restrict__ WeWo,
                      float* __restrict__ WnWo, int* __restrict__ deg, int N) {
    int b = blockIdx.x, tid = threadIdx.x;   // (25 + ceil(N/512)) blocks x 512
    if (b >= 25) {
        int i = (b - 25) * 512 + tid;
        if (i < N) deg[i] = 0;
        return;
    }
    if (b < 16) {
        int t = b * 512 + tid;               // t = (h*64+k)*32 + o
        int j = t >> 5, o = t & 31;
        int h = j >> 6, k = j & 63;
        float a = 0.f;
        for (int d = 0; d < DD; ++d)
            a += We[k * HD + h * DD + d] * Wo[(h * DD + d) * DD + o];
        WeWo[t] = a;
    } else if (b < 24) {
        int u = (b - 16) * 512 + tid;        // u = k*32 + o
        int k = u >> 5, o = u & 31;
        float a = 0.f;
        for (int d = 0; d < HD; ++d)
            a += Wn[k * HD + d] * Wo[d * DD + o];
        WnWo[u] = a;
    } else {
        int k = tid >> 2, h = tid & 3;
        float a = 0.f, bb = 0.f;
        for (int d = 0; d < DD; ++d) {
            float w = Wn[k * HD + h * DD + d];
            a += w * Wa[d];
            bb += w * Wa[DD + d];
        }
        WnA[k * HH + h] = a;
        WnB[k * HH + h] = bb;
        if (k < EDF) {
            float c = 0.f;
            for (int d = 0; d < DD; ++d)
                c += We[k * HD + h * DD + d] * (Wa[d] + Wa[DD + d]);
            WeC[k * HH + h] = c;
        }
    }
}

// ---- per-node attention scalars an,bn (wave per node, grid-stride) ------
__global__ void k_nodes(const float* __restrict__ X, const float* __restrict__ WnA,
                        const float* __restrict__ WnB, float* __restrict__ an,
                        float* __restrict__ bn, int N) {
    int wave = threadIdx.x >> 6, lane = threadIdx.x & 63;
    float4 wa0 = *(const float4*)(WnA + lane * 8);
    float4 wa1 = *(const float4*)(WnA + lane * 8 + 4);
    float4 wb0 = *(const float4*)(WnB + lane * 8);
    float4 wb1 = *(const float4*)(WnB + lane * 8 + 4);
    int stride = gridDim.x * 4;
    for (int n = blockIdx.x * 4 + wave; n < N; n += stride) {
        float2 x2 = *(const float2*)(X + (size_t)n * INF + lane * 2);
        float pa[HH], pb[HH];
        pa[0] = x2.x * wa0.x + x2.y * wa1.x;
        pa[1] = x2.x * wa0.y + x2.y * wa1.y;
        pa[2] = x2.x * wa0.z + x2.y * wa1.z;
        pa[3] = x2.x * wa0.w + x2.y * wa1.w;
        pb[0] = x2.x * wb0.x + x2.y * wb1.x;
        pb[1] = x2.x * wb0.y + x2.y * wb1.y;
        pb[2] = x2.x * wb0.z + x2.y * wb1.z;
        pb[3] = x2.x * wb0.w + x2.y * wb1.w;
#pragma unroll
        for (int off = 32; off; off >>= 1)
#pragma unroll
            for (int h = 0; h < HH; ++h) {
                pa[h] += __shfl_xor(pa[h], off);
                pb[h] += __shfl_xor(pb[h], off);
            }
        if (lane == 0)
#pragma unroll
            for (int h = 0; h < HH; ++h) {
                an[(size_t)n * HH + h] = pa[h];
                bn[(size_t)n * HH + h] = pb[h];
            }
    }
}

// ---- CSR build ----------------------------------------------------------
__global__ void k_hist(const int* __restrict__ dst, int* __restrict__ deg,
                       int* __restrict__ rank, int E) {
    int e = blockIdx.x * blockDim.x + threadIdx.x;
    if (e < E) rank[e] = atomicAdd(&deg[dst[e]], 1);
}
__global__ void k_scan1(const int* __restrict__ deg, int* __restrict__ partial,
                        int N, int chunk) {
    __shared__ int s[256];
    int tid = threadIdx.x;
    int i = blockIdx.x * chunk + tid;
    int v = (tid < chunk && i < N) ? deg[i] : 0;
    s[tid] = v; __syncthreads();
    for (int off = 128; off; off >>= 1) {
        if (tid < off) s[tid] += s[tid + off];
        __syncthreads();
    }
    if (tid == 0) partial[blockIdx.x] = s[0];
}
__global__ void k_scan2(const int* __restrict__ partial, int* __restrict__ pscan) {
    __shared__ int s[NB];
    int tid = threadIdx.x;
    int v = partial[tid];
    s[tid] = v; __syncthreads();
    for (int off = 1; off < NB; off <<= 1) {
        int t = (tid >= off) ? s[tid - off] : 0;
        __syncthreads();
        s[tid] += t;
        __syncthreads();
    }
    pscan[tid] = s[tid] - v;   // exclusive
}
// packs nd[i] = {offs, deg}
__global__ void k_scan3(const int* __restrict__ deg, const int* __restrict__ pscan,
                        int* __restrict__ offs, int2* __restrict__ nd,
                        int N, int chunk) {
    __shared__ int s[256];
    int tid = threadIdx.x;
    int i = blockIdx.x * chunk + tid;
    int v = (tid < chunk && i < N) ? deg[i] : 0;
    s[tid] = v; __syncthreads();
    for (int off = 1; off < 256; off <<= 1) {
        int t = (tid >= off) ? s[tid - off] : 0;
        __syncthreads();
        s[tid] += t;
        __syncthreads();
    }
    if (tid < chunk && i < N) {
        int o = pscan[blockIdx.x] + s[tid] - v;   // exclusive
        offs[i] = o;
        nd[i] = make_int2(o, v);
    }
}
// permutation + an-prescatter: eids[p]=e, anp[p]=an[src[e]]
__global__ void k_perm(const int* __restrict__ src, const int* __restrict__ dst,
                       const int* __restrict__ offs, const int* __restrict__ rank,
                       const float* __restrict__ an, int* __restrict__ eids,
                       float4* __restrict__ anp, int E) {
    int e = blockIdx.x * blockDim.x + threadIdx.x;
    if (e < E) {
        int p = offs[dst[e]] + rank[e];
        eids[p] = e;
        anp[p] = *(const float4*)(an + (size_t)src[e] * HH);
    }
}

// ---- single-pass: logits + softmax + aggregate + epilogue GEMM ----------
// R9's verified structure (166us best) + depth-3 gather prefetch: three
// float4 EF rows in flight per lane (addresses pre-staged in ebuf), to
// cover the residual non-overlapped gather latency.
__global__ void k_agg(const float* __restrict__ EF, const float4* __restrict__ anp,
                      const float* __restrict__ bn, const float* __restrict__ WeC,
                      const int* __restrict__ eids, const int2* __restrict__ nd,
                      const float* __restrict__ WW, const float* __restrict__ X,
                      const float* __restrict__ WnWo, float* __restrict__ out, int N) {
    __shared__ float ww_s[256 * 32];         // WeWo [j][o], 32KB
    __shared__ float pw[4][256];             // per-wave: anp staging / G
    __shared__ int   ebuf[4][CHUNK];
    for (int i = threadIdx.x; i < 256 * 32; i += 256)
        ww_s[i] = WW[i];
    __syncthreads();                         // once per block

    int wave = threadIdx.x >> 6, lane = threadIdx.x & 63;
    int g = lane >> 4, q = lane & 15;
    int r8 = lane >> 3, c4 = (lane & 7) * 4; // epilogue: row-in-group, col base
    // wc[c][h] = WeC[(q*4+c)*4+h]; 1KB, L1-resident
    float4 c0 = *(const float4*)(WeC + (q * 4 + 0) * 4);
    float4 c1 = *(const float4*)(WeC + (q * 4 + 1) * 4);
    float4 c2w = *(const float4*)(WeC + (q * 4 + 2) * 4);
    float4 c3 = *(const float4*)(WeC + (q * 4 + 3) * 4);
    int stride = gridDim.x * 4;
    for (int n = blockIdx.x * 4 + wave; n < N; n += stride) {
        int2 sd = nd[n];
        int st = sd.x, dn = sd.y;
        if (dn == 0) {                       // rare: out = relu(X @ WnWo)
            if (lane < 32) {
                float a = 0.f;
                for (int k = 0; k < INF; ++k)
                    a += X[(size_t)n * INF + k] * WnWo[k * DD + lane];
                out[(size_t)n * DD + lane] = fmaxf(a, 0.f);
            }
            continue;
        }
        float4 bn4 = *(const float4*)(bn + (size_t)n * HH);
        float4* abuf = (float4*)pw[wave];
        float4 gh0 = make_float4(0.f, 0.f, 0.f, 0.f);   // head h, feats 4q..4q+3
        float4 gh1 = gh0, gh2 = gh0, gh3 = gh0;
        float den0 = 0.f, den1 = 0.f, den2 = 0.f, den3 = 0.f;
        for (int r0 = 0; r0 < dn; r0 += CHUNK) {
            int cnt = dn - r0; if (cnt > CHUNK) cnt = CHUNK;
            {
                int l2 = lane < cnt ? lane : cnt - 1;
                ebuf[wave][lane] = eids[st + r0 + l2];
                abuf[lane] = anp[(size_t)(st + r0 + l2)];
            }
            int nb4 = (cnt + 3) >> 2;
            // depth-3 prefetch of 256B rows (group g -> edge i*4+g)
            int e = ebuf[wave][g];
            float4 xA = *(const float4*)(EF + (size_t)e * EDF + q * 4);
            e = ebuf[wave][(4 + g) & 63];
            float4 xB = *(const float4*)(EF + (size_t)e * EDF + q * 4);
            e = ebuf[wave][(8 + g) & 63];
            float4 xC = *(const float4*)(EF + (size_t)e * EDF + q * 4);
            for (int i = 0; i < nb4; ++i) {
                e = ebuf[wave][((i + 3) * 4 + g) & 63];
                float4 xD = *(const float4*)(EF + (size_t)e * EDF + q * 4);
                float4 a4 = abuf[i * 4 + g];         // 16-way LDS broadcast
                bool valid = (i * 4 + g) < cnt;
                // logits: DPP 16-lane reduce of EF . WeC per head
                float ae0 = red16(xA.x * c0.x + xA.y * c1.x + xA.z * c2w.x + xA.w * c3.x);
                float ae1 = red16(xA.x * c0.y + xA.y * c1.y + xA.z * c2w.y + xA.w * c3.y);
                float ae2 = red16(xA.x * c0.z + xA.y * c1.z + xA.z * c2w.z + xA.w * c3.z);
                float ae3 = red16(xA.x * c0.w + xA.y * c1.w + xA.z * c2w.w + xA.w * c3.w);
                float l0 = a4.x + bn4.x + ae0;
                float l1 = a4.y + bn4.y + ae1;
                float l2 = a4.z + bn4.z + ae2;
                float l3 = a4.w + bn4.w + ae3;
                float w0 = valid ? __expf(l0 > 0.f ? l0 : NEG * l0) : 0.f;
                float w1 = valid ? __expf(l1 > 0.f ? l1 : NEG * l1) : 0.f;
                float w2 = valid ? __expf(l2 > 0.f ? l2 : NEG * l2) : 0.f;
                float w3 = valid ? __expf(l3 > 0.f ? l3 : NEG * l3) : 0.f;
                gh0.x += w0 * xA.x; gh0.y += w0 * xA.y; gh0.z += w0 * xA.z; gh0.w += w0 * xA.w;
                gh1.x += w1 * xA.x; gh1.y += w1 * xA.y; gh1.z += w1 * xA.z; gh1.w += w1 * xA.w;
                gh2.x += w2 * xA.x; gh2.y += w2 * xA.y; gh2.z += w2 * xA.z; gh2.w += w2 * xA.w;
                gh3.x += w3 * xA.x; gh3.y += w3 * xA.y; gh3.z += w3 * xA.z; gh3.w += w3 * xA.w;
                den0 += w0; den1 += w1; den2 += w2; den3 += w3;
                xA = xB; xB = xC; xC = xD;
            }
        }
        // cross-group combine (q preserved under xor 16/32)
#pragma unroll
        for (int off = 16; off < 64; off <<= 1) {
            gh0.x += __shfl_xor(gh0.x, off); gh0.y += __shfl_xor(gh0.y, off);
            gh0.z += __shfl_xor(gh0.z, off); gh0.w += __shfl_xor(gh0.w, off);
            gh1.x += __shfl_xor(gh1.x, off); gh1.y += __shfl_xor(gh1.y, off);
            gh1.z += __shfl_xor(gh1.z, off); gh1.w += __shfl_xor(gh1.w, off);
            gh2.x += __shfl_xor(gh2.x, off); gh2.y += __shfl_xor(gh2.y, off);
            gh2.z += __shfl_xor(gh2.z, off); gh2.w += __shfl_xor(gh2.w, off);
            gh3.x += __shfl_xor(gh3.x, off); gh3.y += __shfl_xor(gh3.y, off);
            gh3.z += __shfl_xor(gh3.z, off); gh3.w += __shfl_xor(gh3.w, off);
            den0 += __shfl_xor(den0, off); den1 += __shfl_xor(den1, off);
            den2 += __shfl_xor(den2, off); den3 += __shfl_xor(den3, off);
        }
        // ---- stage normalized G: lane-linear float4 write (no conflicts) -
        float* G = pw[wave];                 // abuf no longer needed
        float dsel = g == 0 ? den0 : g == 1 ? den1 : g == 2 ? den2 : den3;
        float4 gsel = g == 0 ? gh0 : g == 1 ? gh1 : g == 2 ? gh2 : gh3;
        float inv = 1.f / dsel;
        float4 gn;
        gn.x = gsel.x * inv; gn.y = gsel.y * inv;
        gn.z = gsel.z * inv; gn.w = gsel.w * inv;
        *(float4*)&G[lane * 4] = gn;         // lane*4 == g*64+q*4
        // ---- epilogue GEMM: linear WW reads + broadcast G ---------------
        float4 acc = make_float4(0.f, 0.f, 0.f, 0.f);
#pragma unroll 8
        for (int s = 0; s < 32; ++s) {
            int row = s * 8 + r8;
            float gv = G[row];                              // 8-way multicast
            float4 w4 = *(const float4*)&ww_s[row * 32 + c4]; // linear 1KB/instr
            acc.x += gv * w4.x;
            acc.y += gv * w4.y;
            acc.z += gv * w4.z;
            acc.w += gv * w4.w;
        }
#pragma unroll
        for (int off = 8; off < 64; off <<= 1) {
            acc.x += __shfl_xor(acc.x, off);
            acc.y += __shfl_xor(acc.y, off);
            acc.z += __shfl_xor(acc.z, off);
            acc.w += __shfl_xor(acc.w, off);
        }
        if (lane < 8) {
            float4 o_;
            o_.x = fmaxf(acc.x, 0.f);
            o_.y = fmaxf(acc.y, 0.f);
            o_.z = fmaxf(acc.z, 0.f);
            o_.w = fmaxf(acc.w, 0.f);
            *(float4*)(out + (size_t)n * DD + lane * 4) = o_;
        }
    }
}

extern "C" void kernel_launch(void* const* d_in, const int* in_sizes, int n_in,
                              void* d_out, int out_size, void* d_ws, size_t ws_size,
                              hipStream_t stream) {
    const float* node_feats = (const float*)d_in[0];
    const float* edge_feats = (const float*)d_in[1];
    const int*   src        = (const int*)d_in[2];
    const int*   dst        = (const int*)d_in[3];
    const float* Wn         = (const float*)d_in[4];
    const float* We         = (const float*)d_in[5];
    const float* Wa         = (const float*)d_in[6];
    const float* Wo         = (const float*)d_in[7];
    float* out = (float*)d_out;
    int N = in_sizes[0] / INF;
    int E = in_sizes[2];

    char* p = (char*)d_ws;
    auto alloc = [&](size_t bytes) {
        char* r = p;
        p += (bytes + 255) & ~(size_t)255;
        return r;
    };
    float* WnA    = (float*)alloc((size_t)INF * HH * 4);
    float* WnB    = (float*)alloc((size_t)INF * HH * 4);
    float* WeC    = (float*)alloc((size_t)EDF * HH * 4);
    float* WeWo   = (float*)alloc((size_t)EDF * HH * DD * 4);
    float* WnWo   = (float*)alloc((size_t)INF * DD * 4);
    float* an     = (float*)alloc((size_t)N * HH * 4);
    float* bn     = (float*)alloc((size_t)N * HH * 4);
    float4* anp   = (float4*)alloc((size_t)E * 16);
    int* deg      = (int*)alloc((size_t)N * 4);
    int* offs     = (int*)alloc((size_t)N * 4);
    int2* nd      = (int2*)alloc((size_t)N * 8);
    int* rank     = (int*)alloc((size_t)E * 4);
    int* eids     = (int*)alloc((size_t)E * 4);
    int* partial  = (int*)alloc((size_t)NB * 4);
    int* pscan    = (int*)alloc((size_t)NB * 4);

    int chunk = (N + NB - 1) / NB;
    int preblk = 25 + (N + 511) / 512;

    hipLaunchKernelGGL(k_pre, dim3(preblk), dim3(512), 0, stream,
                       Wn, We, Wa, Wo, WnA, WnB, WeC, WeWo, WnWo, deg, N);
    hipLaunchKernelGGL(k_nodes, dim3(GS_NODES), dim3(256), 0, stream,
                       node_feats, WnA, WnB, an, bn, N);
    hipLaunchKernelGGL(k_hist, dim3((E + 255) / 256), dim3(256), 0, stream,
                       dst, deg, rank, E);
    hipLaunchKernelGGL(k_scan1, dim3(NB), dim3(256), 0, stream, deg, partial, N, chunk);
    hipLaunchKernelGGL(k_scan2, dim3(1), dim3(NB), 0, stream, partial, pscan);
    hipLaunchKernelGGL(k_scan3, dim3(NB), dim3(256), 0, stream, deg, pscan, offs, nd, N, chunk);
    hipLaunchKernelGGL(k_perm, dim3((E + 255) / 256), dim3(256), 0, stream,
                       src, dst, offs, rank, an, eids, anp, E);
    hipLaunchKernelGGL(k_agg, dim3(GS_AGG), dim3(256), 0, stream,
                       edge_feats, anp, bn, WeC, eids, nd, WeWo, node_feats, WnWo, out, N);
}